// Round 4
// baseline (786.816 us; speedup 1.0000x reference)
//
#include <hip/hip_runtime.h>

// ---------------------------------------------------------------------------
// GraphSAGE 3-layer forward.
//   CSR build -> bf16 planes -> per-layer FUSED: gather-mean (16-deep MLP)
//   + MFMA GEMM [agg(hi/lo)|z(bf16)]@[Wl;Wr]^T + bias + L2norm + relu
//   -> final linear (bf16 z).
// ---------------------------------------------------------------------------

typedef __bf16 bf16x8 __attribute__((ext_vector_type(8)));
typedef float  f32x4  __attribute__((ext_vector_type(4)));

#define MFMA16(a, b, c) __builtin_amdgcn_mfma_f32_16x16x32_bf16((a), (b), (c), 0, 0, 0)

__device__ __forceinline__ unsigned rne_bf16(float f) {
  unsigned u = __float_as_uint(f);
  unsigned r = u + 0x7FFFu + ((u >> 16) & 1u);
  return r >> 16;
}

__device__ __forceinline__ float bf_lo(unsigned u) { return __uint_as_float(u << 16); }
__device__ __forceinline__ float bf_hi(unsigned u) { return __uint_as_float(u & 0xFFFF0000u); }

// ---------------- CSR build ----------------

__global__ void count_deg_k(const int* __restrict__ dst, int* __restrict__ cnt, int E) {
  int e = blockIdx.x * 256 + threadIdx.x;
  if (e < E) atomicAdd(&cnt[dst[e]], 1);
}

__global__ void scan1_k(const int* __restrict__ cnt, int* __restrict__ bsums, int n) {
  __shared__ int sd[256];
  int base = blockIdx.x * 2048 + threadIdx.x * 8;
  int t = 0;
#pragma unroll
  for (int i = 0; i < 8; i++) { int idx = base + i; if (idx < n) t += cnt[idx]; }
  sd[threadIdx.x] = t; __syncthreads();
  for (int off = 128; off > 0; off >>= 1) {
    if (threadIdx.x < off) sd[threadIdx.x] += sd[threadIdx.x + off];
    __syncthreads();
  }
  if (threadIdx.x == 0) bsums[blockIdx.x] = sd[0];
}

__global__ void scan2_k(int* bsums, int nb) {
  if (blockIdx.x == 0 && threadIdx.x == 0) {
    int run = 0;
    for (int b = 0; b < nb; b++) { int t = bsums[b]; bsums[b] = run; run += t; }
  }
}

__global__ void scan3_k(const int* __restrict__ cnt, const int* __restrict__ bsums,
                        int* __restrict__ offsets, int* __restrict__ cursor,
                        float* __restrict__ inv_cnt, int n, int E) {
  __shared__ int sd[256];
  int base = blockIdx.x * 2048 + threadIdx.x * 8;
  int loc[8]; int t = 0;
#pragma unroll
  for (int i = 0; i < 8; i++) { int idx = base + i; loc[i] = (idx < n) ? cnt[idx] : 0; t += loc[i]; }
  sd[threadIdx.x] = t; __syncthreads();
  for (int off = 1; off < 256; off <<= 1) {
    int u = (threadIdx.x >= (unsigned)off) ? sd[threadIdx.x - off] : 0;
    __syncthreads();
    sd[threadIdx.x] += u;
    __syncthreads();
  }
  int run = bsums[blockIdx.x] + sd[threadIdx.x] - t;
#pragma unroll
  for (int i = 0; i < 8; i++) {
    int idx = base + i;
    if (idx < n) {
      offsets[idx] = run;
      cursor[idx]  = run;
      int c = loc[i] > 1 ? loc[i] : 1;
      inv_cnt[idx] = 1.0f / (float)c;
      run += loc[i];
    }
  }
  if (blockIdx.x == 0 && threadIdx.x == 0) offsets[n] = E;
}

__global__ void bucket_k(const int* __restrict__ src, const int* __restrict__ dst,
                         int* __restrict__ cursor, int* __restrict__ esrc, int E) {
  int e = blockIdx.x * 256 + threadIdx.x;
  if (e < E) {
    int d = dst[e];
    int pos = atomicAdd(&cursor[d], 1);
    esrc[pos] = src[e];
  }
}

// ---------------- fp32 -> bf16 plane ----------------
__global__ void to_bf16_k(const float4* __restrict__ in, uint2* __restrict__ out, int n4) {
  int i = blockIdx.x * 256 + threadIdx.x;
  if (i >= n4) return;
  float4 f = in[i];
  uint2 o;
  o.x = rne_bf16(f.x) | (rne_bf16(f.y) << 16);
  o.y = rne_bf16(f.z) | (rne_bf16(f.w) << 16);
  out[i] = o;
}

// ---------------- weight fragment prep (hi/lo bf16, MFMA B-layout) ----------
__global__ void wfrag_prep_k(const float* __restrict__ Wl, const float* __restrict__ Wr,
                             unsigned short* __restrict__ wfrag) {
  int id = blockIdx.x * 256 + threadIdx.x;
  if (id >= 3 * 2 * 8 * 8 * 64) return;
  int l = id & 63;
  int c = (id >> 6) & 7;
  int t = (id >> 9) & 7;
  int p = (id >> 12) & 1;
  int layer = id >> 13;
  int col = t * 16 + (l & 15);
  int kbase = c * 32 + (l >> 4) * 8;
  unsigned short* dst = wfrag + (size_t)layer * 65536 +
                        ((((size_t)p * 8 + t) * 8 + c) * 64 + l) * 8;
#pragma unroll
  for (int j = 0; j < 8; ++j) {
    int k = kbase + j;
    float w = (k < 128) ? Wl[layer * 16384 + col * 128 + k]
                        : Wr[layer * 16384 + col * 128 + (k - 128)];
    unsigned h = rne_bf16(w);
    unsigned o;
    if (p == 0) o = h;
    else o = rne_bf16(w - __uint_as_float(h << 16));
    dst[j] = (unsigned short)o;
  }
}

// WlinT[k*40+c] = Wlin[c*128+k]
__global__ void transpose_lin_k(const float* __restrict__ Wlin, float* __restrict__ WlinT) {
  int idx = blockIdx.x * 256 + threadIdx.x;
  if (idx >= 40 * 128) return;
  int c = idx >> 7; int k = idx & 127;
  WlinT[k * 40 + c] = Wlin[idx];
}

// ---------------- FUSED SAGE layer: gather-mean + MFMA GEMM + norm ----------
// Block: 256 threads = 4 waves; 32 nodes/tile.
// Gather: wave wv owns nodes v0+wv*8 .. +7; 8 nodes x 2 edges interleaved
// (16-deep MLP), fp32 accumulate, hi/lo split direct to swizzled LDS.
// GEMM: wave wv owns 2 col-tiles; K=256 (agg hi/lo + z bf16).
__global__ __launch_bounds__(256, 2) void sage_fused_k(
    const unsigned short* __restrict__ zb,
    const int* __restrict__ offsets, const int* __restrict__ esrc,
    const float* __restrict__ inv_cnt,
    const unsigned short* __restrict__ wf, const float* __restrict__ bl,
    unsigned short* __restrict__ out_bf, int n, int E, int ntiles) {
  __shared__ unsigned short Ah_s[32 * 256];   // 16 KB swizzled [32][256]
  __shared__ unsigned short Al_s[32 * 128];   // 8 KB  swizzled [32][128]
  __shared__ float psum[2][4][16];

  const int lane = threadIdx.x & 63;
  const int wv = threadIdx.x >> 6;
  const int g = lane >> 4;
  const int rl = lane & 15;

  const bf16x8* wfv = (const bf16x8*)wf;
  const int t0 = wv * 2, t1 = wv * 2 + 1;
  bf16x8 Bh0[8], Bh1[8], Bl0[8], Bl1[8];
#pragma unroll
  for (int c = 0; c < 8; ++c) {
    Bh0[c] = wfv[((0 * 8 + t0) * 8 + c) * 64 + lane];
    Bh1[c] = wfv[((0 * 8 + t1) * 8 + c) * 64 + lane];
    Bl0[c] = wfv[((1 * 8 + t0) * 8 + c) * 64 + lane];
    Bl1[c] = wfv[((1 * 8 + t1) * 8 + c) * 64 + lane];
  }
  const float b0 = bl[t0 * 16 + rl];
  const float b1 = bl[t1 * 16 + rl];

  char* pAh = (char*)Ah_s;
  char* pAl = (char*)Al_s;

  for (int tile = blockIdx.x; tile < ntiles; tile += gridDim.x) {
    const int v0 = tile * 32;

    // ---- issue z-half copy loads early (consumed after gather)
    uint4 zpre[2]; int zbyte[2];
#pragma unroll
    for (int q = 0; q < 2; ++q) {
      int lin = q * 2048 + threadIdx.x * 8;   // ushort idx in [32][128]
      int r = lin >> 7, col = lin & 127;
      int v = v0 + r; if (v >= n) v = n - 1;
      zpre[q] = *(const uint4*)(zb + (size_t)v * 128 + col);
      zbyte[q] = (r * 512 + 256 + col * 2) ^ ((r & 7) << 4);
    }

    // ---- gather-mean for this wave's 8 nodes, 2 edge streams each
    int beg[8], deg[8];
    int md = 0;
#pragma unroll
    for (int i = 0; i < 8; ++i) {
      int v = v0 + wv * 8 + i; if (v >= n) v = n - 1;
      int b = __builtin_amdgcn_readfirstlane(offsets[v]);
      int en = __builtin_amdgcn_readfirstlane(offsets[v + 1]);
      beg[i] = b; deg[i] = en - b;
      md = md > deg[i] ? md : deg[i];
    }
    float axA[8], ayA[8], axB[8], ayB[8];
#pragma unroll
    for (int i = 0; i < 8; ++i) { axA[i] = ayA[i] = axB[i] = ayB[i] = 0.f; }

    for (int t = 0; t < md; t += 2) {
#pragma unroll
      for (int i = 0; i < 8; ++i) {
        int d = deg[i];
        int tA = t < d ? t : (d - 1); tA = tA < 0 ? 0 : tA;
        int tB = (t + 1) < d ? (t + 1) : (d - 1); tB = tB < 0 ? 0 : tB;
        float mA = t < d ? 1.f : 0.f;
        float mB = (t + 1) < d ? 1.f : 0.f;
        int iA = beg[i] + tA; iA = iA < E ? iA : (E - 1);
        int iB = beg[i] + tB; iB = iB < E ? iB : (E - 1);
        int sA = __builtin_amdgcn_readfirstlane(esrc[iA]);
        int sB = __builtin_amdgcn_readfirstlane(esrc[iB]);
        sA = (sA >= 0 && sA < n) ? sA : 0;
        sB = (sB >= 0 && sB < n) ? sB : 0;
        unsigned uA = *(const unsigned*)(zb + (size_t)sA * 128 + lane * 2);
        unsigned uB = *(const unsigned*)(zb + (size_t)sB * 128 + lane * 2);
        axA[i] = fmaf(mA, bf_lo(uA), axA[i]);
        ayA[i] = fmaf(mA, bf_hi(uA), ayA[i]);
        axB[i] = fmaf(mB, bf_lo(uB), axB[i]);
        ayB[i] = fmaf(mB, bf_hi(uB), ayB[i]);
      }
    }

    // ---- write agg rows (hi/lo split) to swizzled LDS
#pragma unroll
    for (int i = 0; i < 8; ++i) {
      int v = v0 + wv * 8 + i; if (v >= n) v = n - 1;
      float ic = inv_cnt[v];
      float ax = (axA[i] + axB[i]) * ic;
      float ay = (ayA[i] + ayB[i]) * ic;
      unsigned h0 = rne_bf16(ax), h1 = rne_bf16(ay);
      unsigned l0 = rne_bf16(ax - __uint_as_float(h0 << 16));
      unsigned l1 = rne_bf16(ay - __uint_as_float(h1 << 16));
      int r = wv * 8 + i;
      int swz = (r & 7) << 4;
      *(unsigned*)(pAh + ((r * 512 + lane * 4) ^ swz)) = h0 | (h1 << 16);
      *(unsigned*)(pAl + ((r * 256 + lane * 4) ^ swz)) = l0 | (l1 << 16);
    }
    // ---- commit z-half copy
    *(uint4*)(pAh + zbyte[0]) = zpre[0];
    *(uint4*)(pAh + zbyte[1]) = zpre[1];
    __syncthreads();

    // ---- GEMM + bias + L2norm + relu
#pragma unroll
    for (int s = 0; s < 2; ++s) {
      f32x4 a0 = {0.f, 0.f, 0.f, 0.f};
      f32x4 a1 = {0.f, 0.f, 0.f, 0.f};
      const int rowH = (s * 16 + rl) * 512;
      const int rowL = (s * 16 + rl) * 256;
      const int swz = (rl & 7) << 4;
#pragma unroll
      for (int c = 0; c < 4; ++c) {           // agg half: hi/lo
        int offH = (rowH + c * 64 + g * 16) ^ swz;
        int offL = (rowL + c * 64 + g * 16) ^ swz;
        bf16x8 ah = *(const bf16x8*)(pAh + offH);
        bf16x8 al = *(const bf16x8*)(pAl + offL);
        a0 = MFMA16(ah, Bh0[c], a0); a1 = MFMA16(ah, Bh1[c], a1);
        a0 = MFMA16(ah, Bl0[c], a0); a1 = MFMA16(ah, Bl1[c], a1);
        a0 = MFMA16(al, Bh0[c], a0); a1 = MFMA16(al, Bh1[c], a1);
      }
#pragma unroll
      for (int c = 4; c < 8; ++c) {           // z half: single bf16
        int offH = (rowH + c * 64 + g * 16) ^ swz;
        bf16x8 ah = *(const bf16x8*)(pAh + offH);
        a0 = MFMA16(ah, Bh0[c], a0); a1 = MFMA16(ah, Bh1[c], a1);
        a0 = MFMA16(ah, Bl0[c], a0); a1 = MFMA16(ah, Bl1[c], a1);
      }
      float pr[4];
#pragma unroll
      for (int j = 0; j < 4; ++j) {
        a0[j] += b0; a1[j] += b1;
        pr[j] = a0[j] * a0[j] + a1[j] * a1[j];
      }
#pragma unroll
      for (int m = 1; m < 16; m <<= 1) {
#pragma unroll
        for (int j = 0; j < 4; ++j) pr[j] += __shfl_xor(pr[j], m);
      }
      if (rl == 0) {
#pragma unroll
        for (int j = 0; j < 4; ++j) psum[s][wv][g * 4 + j] = pr[j];
      }
      __syncthreads();
#pragma unroll
      for (int j = 0; j < 4; ++j) {
        int row16 = g * 4 + j;
        float tot = psum[s][0][row16] + psum[s][1][row16] +
                    psum[s][2][row16] + psum[s][3][row16];
        float inv = 1.0f / fmaxf(sqrtf(tot), 1e-12f);
        int v = v0 + s * 16 + row16;
        if (v < n) {
          float o0 = fmaxf(a0[j] * inv, 0.f);
          float o1 = fmaxf(a1[j] * inv, 0.f);
          out_bf[(size_t)v * 128 + t0 * 16 + rl] = (unsigned short)rne_bf16(o0);
          out_bf[(size_t)v * 128 + t1 * 16 + rl] = (unsigned short)rne_bf16(o1);
        }
      }
    }
    __syncthreads();
  }
}

// ---------------- final linear: [N,128](bf16) @ [128,40] + b ----------------
__global__ __launch_bounds__(256) void final_linear_k(
    const unsigned short* __restrict__ zb, const float* __restrict__ WlinT,
    const float* __restrict__ blin, float* __restrict__ out, int n) {
  __shared__ float wt[128 * 40 + 64];
  __shared__ float bs[40];
  for (int i = threadIdx.x; i < 128 * 40; i += 256) wt[i] = WlinT[i];
  if (threadIdx.x < 40) bs[threadIdx.x] = blin[threadIdx.x];
  __syncthreads();

  int lane = threadIdx.x & 63;
  int c = lane < 40 ? lane : 0;
  int wid = (blockIdx.x * 256 + threadIdx.x) >> 6;
  int nw = (gridDim.x * 256) >> 6;
  for (int v = wid; v < n; v += nw) {
    unsigned u = *(const unsigned*)(zb + (size_t)v * 128 + lane * 2);
    float acc = bs[c];
#pragma unroll 16
    for (int k = 0; k < 64; k++) {
      unsigned w0 = (unsigned)__builtin_amdgcn_readlane((int)u, k);
      acc = fmaf(bf_lo(w0), wt[(2 * k) * 40 + c], acc);
      acc = fmaf(bf_hi(w0), wt[(2 * k + 1) * 40 + c], acc);
    }
    if (lane < 40) out[(size_t)v * 40 + lane] = acc;
  }
}

// ---------------- launch ----------------

extern "C" void kernel_launch(void* const* d_in, const int* in_sizes, int n_in,
                              void* d_out, int out_size, void* d_ws, size_t ws_size,
                              hipStream_t stream) {
  const float* x    = (const float*)d_in[0];
  const int*   ei   = (const int*)d_in[1];
  const float* Wl   = (const float*)d_in[2];
  const float* bl   = (const float*)d_in[3];
  const float* Wr   = (const float*)d_in[4];
  const float* Wlin = (const float*)d_in[5];
  const float* blin = (const float*)d_in[6];

  const int N = in_sizes[0] / 128;
  const int E = in_sizes[1] / 2;
  const int D = 128;

  const int* src = ei;
  const int* dstp = ei + E;

  // workspace layout
  unsigned short* planeA = (unsigned short*)d_ws;            // N*128 bf16
  unsigned short* planeB = planeA + (size_t)N * D;           // N*128 bf16
  float* inv_cnt = (float*)(planeB + (size_t)N * D);         // N
  float* WlinT   = inv_cnt + N;                              // 5120
  unsigned short* Wfrag = (unsigned short*)(WlinT + 5120);   // 3*65536
  int*   offsets = (int*)(Wfrag + 3 * 65536);                // N+1
  int*   cursor  = offsets + N + 1;                          // N
  int*   esrc    = cursor + N;                               // E
  int*   bsums   = esrc + E;                                 // <=64

  const int nb = (N + 2047) / 2048;

  // CSR build
  hipMemsetAsync(cursor, 0, (size_t)N * 4, stream);
  count_deg_k<<<(E + 255) / 256, 256, 0, stream>>>(dstp, cursor, E);
  scan1_k<<<nb, 256, 0, stream>>>(cursor, bsums, N);
  scan2_k<<<1, 64, 0, stream>>>(bsums, nb);
  scan3_k<<<nb, 256, 0, stream>>>(cursor, bsums, offsets, cursor, inv_cnt, N, E);
  bucket_k<<<(E + 255) / 256, 256, 0, stream>>>(src, dstp, cursor, esrc, E);

  // weight prep + bf16 x plane
  wfrag_prep_k<<<96, 256, 0, stream>>>(Wl, Wr, Wfrag);
  transpose_lin_k<<<(40 * 128 + 255) / 256, 256, 0, stream>>>(Wlin, WlinT);
  to_bf16_k<<<((N * 32) + 255) / 256, 256, 0, stream>>>((const float4*)x, (uint2*)planeA, N * 32);

  const int ntiles = (N + 31) / 32;

  // fused layers
  sage_fused_k<<<ntiles, 256, 0, stream>>>(planeA, offsets, esrc, inv_cnt,
                                           Wfrag + 0 * 65536, bl + 0 * D, planeB, N, E, ntiles);
  sage_fused_k<<<ntiles, 256, 0, stream>>>(planeB, offsets, esrc, inv_cnt,
                                           Wfrag + 1 * 65536, bl + 1 * D, planeA, N, E, ntiles);
  sage_fused_k<<<ntiles, 256, 0, stream>>>(planeA, offsets, esrc, inv_cnt,
                                           Wfrag + 2 * 65536, bl + 2 * D, planeB, N, E, ntiles);

  // final linear
  final_linear_k<<<2048, 256, 0, stream>>>(planeB, WlinT, blin, (float*)d_out, N);
}

// Round 5
// 546.710 us; speedup vs baseline: 1.4392x; 1.4392x over previous
//
#include <hip/hip_runtime.h>

// ---------------------------------------------------------------------------
// GraphSAGE 3-layer forward.
//   CSR build (two-pass LDS-staged bucket) -> bf16 planes -> per-layer:
//   aggregate(mean, half-wave rows) -> MFMA GEMM [agg(hi/lo)|z(bf16)]@[Wl;Wr]^T
//   + bias + L2norm + relu -> final linear.
// ---------------------------------------------------------------------------

typedef __bf16 bf16x8 __attribute__((ext_vector_type(8)));
typedef float  f32x4  __attribute__((ext_vector_type(4)));

#define MFMA16(a, b, c) __builtin_amdgcn_mfma_f32_16x16x32_bf16((a), (b), (c), 0, 0, 0)

__device__ __forceinline__ unsigned rne_bf16(float f) {
  unsigned u = __float_as_uint(f);
  unsigned r = u + 0x7FFFu + ((u >> 16) & 1u);
  return r >> 16;
}

__device__ __forceinline__ float bf_lo(unsigned u) { return __uint_as_float(u << 16); }
__device__ __forceinline__ float bf_hi(unsigned u) { return __uint_as_float(u & 0xFFFF0000u); }

// ---------------- CSR build ----------------

__global__ void count_deg_k(const int* __restrict__ dst, int* __restrict__ cnt, int E) {
  int e = blockIdx.x * 256 + threadIdx.x;
  if (e < E) atomicAdd(&cnt[dst[e]], 1);
}

__global__ void scan1_k(const int* __restrict__ cnt, int* __restrict__ bsums, int n) {
  __shared__ int sd[256];
  int base = blockIdx.x * 2048 + threadIdx.x * 8;
  int t = 0;
#pragma unroll
  for (int i = 0; i < 8; i++) { int idx = base + i; if (idx < n) t += cnt[idx]; }
  sd[threadIdx.x] = t; __syncthreads();
  for (int off = 128; off > 0; off >>= 1) {
    if (threadIdx.x < off) sd[threadIdx.x] += sd[threadIdx.x + off];
    __syncthreads();
  }
  if (threadIdx.x == 0) bsums[blockIdx.x] = sd[0];
}

__global__ void scan2_k(int* bsums, int nb) {
  if (blockIdx.x == 0 && threadIdx.x == 0) {
    int run = 0;
    for (int b = 0; b < nb; b++) { int t = bsums[b]; bsums[b] = run; run += t; }
  }
}

__global__ void scan3_k(const int* __restrict__ cnt, const int* __restrict__ bsums,
                        int* __restrict__ offsets, float* __restrict__ inv_cnt,
                        int n, int E) {
  __shared__ int sd[256];
  int base = blockIdx.x * 2048 + threadIdx.x * 8;
  int loc[8]; int t = 0;
#pragma unroll
  for (int i = 0; i < 8; i++) { int idx = base + i; loc[i] = (idx < n) ? cnt[idx] : 0; t += loc[i]; }
  sd[threadIdx.x] = t; __syncthreads();
  for (int off = 1; off < 256; off <<= 1) {
    int u = (threadIdx.x >= (unsigned)off) ? sd[threadIdx.x - off] : 0;
    __syncthreads();
    sd[threadIdx.x] += u;
    __syncthreads();
  }
  int run = bsums[blockIdx.x] + sd[threadIdx.x] - t;
#pragma unroll
  for (int i = 0; i < 8; i++) {
    int idx = base + i;
    if (idx < n) {
      offsets[idx] = run;
      int c = loc[i] > 1 ? loc[i] : 1;
      inv_cnt[idx] = 1.0f / (float)c;
      run += loc[i];
    }
  }
  if (blockIdx.x == 0 && threadIdx.x == 0) offsets[n] = E;
}

// gcur[b] = offsets[min(b*1024, N)]
__global__ void gcur_init_k(const int* __restrict__ offsets, int* __restrict__ gcur,
                            int n, int nc) {
  int b = threadIdx.x;
  if (b < nc) {
    int v = b * 1024; if (v > n) v = n;
    gcur[b] = offsets[v];
  }
}

// ---- bucket pass A: coarse bucket by dst>>10, LDS-staged, contiguous flush
// pack = src | ((dst & 1023) << 17); requires N < 2^17.
__global__ __launch_bounds__(256) void bucketA_k(
    const int* __restrict__ src, const int* __restrict__ dst,
    int* __restrict__ gcur, unsigned* __restrict__ coarse, int E, int nc) {
  __shared__ int hist[128];
  __shared__ int sd[128];
  __shared__ int lpos[128];
  __shared__ int gbase[128];
  __shared__ unsigned stage[2048];
  __shared__ unsigned char sbuck[2048];

  const int tid = threadIdx.x;
  const int e0 = blockIdx.x * 2048;

  if (tid < 128) hist[tid] = 0;
  __syncthreads();

  int sv[8], bv[8], pk[8];
#pragma unroll
  for (int j = 0; j < 8; ++j) {
    int e = e0 + j * 256 + tid;
    bv[j] = -1;
    if (e < E) {
      int s = src[e], d = dst[e];
      bv[j] = d >> 10;
      pk[j] = s | ((d & 1023) << 17);
      sv[j] = 1;
      atomicAdd(&hist[bv[j]], 1);
    }
  }
  __syncthreads();

  // inclusive scan of hist[128] (Hillis-Steele in LDS)
  if (tid < 128) sd[tid] = hist[tid];
  __syncthreads();
  for (int off = 1; off < 128; off <<= 1) {
    int t = 0;
    if (tid < 128 && tid >= off) t = sd[tid - off];
    __syncthreads();
    if (tid < 128) sd[tid] += t;
    __syncthreads();
  }
  if (tid < 128) {
    int excl = sd[tid] - hist[tid];
    lpos[tid] = excl;
    gbase[tid] = (tid < nc && hist[tid] > 0) ? atomicAdd(&gcur[tid], hist[tid]) : 0;
  }
  __syncthreads();

  // local bucket-sort into stage
#pragma unroll
  for (int j = 0; j < 8; ++j) {
    if (bv[j] >= 0) {
      int slot = atomicAdd(&lpos[bv[j]], 1);
      stage[slot] = (unsigned)pk[j];
      sbuck[slot] = (unsigned char)bv[j];
    }
  }
  __syncthreads();

  const int total = sd[127];
  for (int i = tid; i < total; i += 256) {
    int b = sbuck[i];
    int excl = sd[b] - hist[b];
    coarse[gbase[b] + (i - excl)] = stage[i];
  }
}

// ---- bucket pass B: one block per coarse bucket, LDS per-node cursors
__global__ __launch_bounds__(256) void bucketB_k(
    const int* __restrict__ offsets, const unsigned* __restrict__ coarse,
    int* __restrict__ esrc, int n) {
  __shared__ int cur[1024];
  const int b = blockIdx.x;
  const int base = b * 1024;
  const int nn = (n - base < 1024) ? (n - base) : 1024;
  for (int j = threadIdx.x; j < nn; j += 256) cur[j] = offsets[base + j];
  __syncthreads();
  const int beg = offsets[base];
  const int end = offsets[base + nn];
  for (int idx = beg + threadIdx.x; idx < end; idx += 256) {
    unsigned p = coarse[idx];
    int dl = (int)(p >> 17);
    int s = (int)(p & 0x1FFFFu);
    int pos = atomicAdd(&cur[dl], 1);
    esrc[pos] = s;
  }
}

// ---------------- fp32 -> bf16 plane ----------------
__global__ void to_bf16_k(const float4* __restrict__ in, uint2* __restrict__ out, int n4) {
  int i = blockIdx.x * 256 + threadIdx.x;
  if (i >= n4) return;
  float4 f = in[i];
  uint2 o;
  o.x = rne_bf16(f.x) | (rne_bf16(f.y) << 16);
  o.y = rne_bf16(f.z) | (rne_bf16(f.w) << 16);
  out[i] = o;
}

// ---------------- weight fragment prep (hi/lo bf16, MFMA B-layout) ----------
__global__ void wfrag_prep_k(const float* __restrict__ Wl, const float* __restrict__ Wr,
                             unsigned short* __restrict__ wfrag) {
  int id = blockIdx.x * 256 + threadIdx.x;
  if (id >= 3 * 2 * 8 * 8 * 64) return;
  int l = id & 63;
  int c = (id >> 6) & 7;
  int t = (id >> 9) & 7;
  int p = (id >> 12) & 1;
  int layer = id >> 13;
  int col = t * 16 + (l & 15);
  int kbase = c * 32 + (l >> 4) * 8;
  unsigned short* dst = wfrag + (size_t)layer * 65536 +
                        ((((size_t)p * 8 + t) * 8 + c) * 64 + l) * 8;
#pragma unroll
  for (int j = 0; j < 8; ++j) {
    int k = kbase + j;
    float w = (k < 128) ? Wl[layer * 16384 + col * 128 + k]
                        : Wr[layer * 16384 + col * 128 + (k - 128)];
    unsigned h = rne_bf16(w);
    unsigned o;
    if (p == 0) o = h;
    else o = rne_bf16(w - __uint_as_float(h << 16));
    dst[j] = (unsigned short)o;
  }
}

// WlinT[k*40+c] = Wlin[c*128+k]
__global__ void transpose_lin_k(const float* __restrict__ Wlin, float* __restrict__ WlinT) {
  int idx = blockIdx.x * 256 + threadIdx.x;
  if (idx >= 40 * 128) return;
  int c = idx >> 7; int k = idx & 127;
  WlinT[k * 40 + c] = Wlin[idx];
}

// ---------------- aggregation: one wave per node, 2 rows per load ----------
// Half-wave h (lanes h*32..h*32+31) reads edge stream beg+2t+h; each lane
// covers dims [4*l32, 4*l32+4) via one uint2 (4 bf16). Combine via shfl_xor(32).
__global__ void aggregate_k(const unsigned short* __restrict__ zb,
                            const int* __restrict__ offsets,
                            const int* __restrict__ esrc,
                            const float* __restrict__ inv_cnt,
                            float* __restrict__ agg, int n) {
  int w = (blockIdx.x * 256 + threadIdx.x) >> 6;
  int lane = threadIdx.x & 63;
  if (w >= n) return;
  int beg = offsets[w], end = offsets[w + 1];
  int cnt = end - beg;
  int half = lane >> 5;
  int l32 = lane & 31;
  float a0 = 0.f, a1 = 0.f, a2 = 0.f, a3 = 0.f;
  int t = 0;
  for (; t + 8 <= cnt; t += 8) {
#pragma unroll
    for (int u = 0; u < 4; ++u) {
      int s = esrc[beg + t + 2 * u + half];
      uint2 d = *(const uint2*)(zb + (size_t)s * 128 + l32 * 4);
      a0 += bf_lo(d.x); a1 += bf_hi(d.x);
      a2 += bf_lo(d.y); a3 += bf_hi(d.y);
    }
  }
  for (; t < cnt; t += 2) {
    int e = t + half;
    float m = (e < cnt) ? 1.f : 0.f;
    int ec = (e < cnt) ? (beg + e) : (end - 1);
    int s = esrc[ec];
    uint2 d = *(const uint2*)(zb + (size_t)s * 128 + l32 * 4);
    a0 = fmaf(m, bf_lo(d.x), a0); a1 = fmaf(m, bf_hi(d.x), a1);
    a2 = fmaf(m, bf_lo(d.y), a2); a3 = fmaf(m, bf_hi(d.y), a3);
  }
  a0 += __shfl_xor(a0, 32); a1 += __shfl_xor(a1, 32);
  a2 += __shfl_xor(a2, 32); a3 += __shfl_xor(a3, 32);
  if (half == 0) {
    float ic = inv_cnt[w];
    float4 o = make_float4(a0 * ic, a1 * ic, a2 * ic, a3 * ic);
    *(float4*)(agg + (size_t)w * 128 + l32 * 4) = o;
  }
}

// ---------------- SAGE layer via MFMA ----------------
// out_bf = bf16(relu(l2norm([agg|zb] @ [Wl;Wr]^T + bl)))
__global__ __launch_bounds__(256, 2) void sage_layer_mfma_k(
    const unsigned short* __restrict__ zb, const float* __restrict__ agg,
    const unsigned short* __restrict__ wf, const float* __restrict__ bl,
    unsigned short* __restrict__ out_bf, int n, int ntiles) {
  __shared__ unsigned short Ah_s[32 * 256];   // 16 KB swizzled [32][256]
  __shared__ unsigned short Al_s[32 * 128];   // 8 KB  swizzled [32][128]
  __shared__ float psum[2][4][16];

  const int lane = threadIdx.x & 63;
  const int wv = threadIdx.x >> 6;
  const int g = lane >> 4;
  const int rl = lane & 15;

  const bf16x8* wfv = (const bf16x8*)wf;
  const int t0 = wv * 2, t1 = wv * 2 + 1;
  bf16x8 Bh0[8], Bh1[8], Bl0[8], Bl1[8];
#pragma unroll
  for (int c = 0; c < 8; ++c) {
    Bh0[c] = wfv[((0 * 8 + t0) * 8 + c) * 64 + lane];
    Bh1[c] = wfv[((0 * 8 + t1) * 8 + c) * 64 + lane];
    Bl0[c] = wfv[((1 * 8 + t0) * 8 + c) * 64 + lane];
    Bl1[c] = wfv[((1 * 8 + t1) * 8 + c) * 64 + lane];
  }
  const float b0 = bl[t0 * 16 + rl];
  const float b1 = bl[t1 * 16 + rl];

  char* pAh = (char*)Ah_s;
  char* pAl = (char*)Al_s;

  for (int tile = blockIdx.x; tile < ntiles; tile += gridDim.x) {
    const int v0 = tile * 32;

    // ---- stage agg rows (hi/lo split), k in [0,128)
#pragma unroll
    for (int q = 0; q < 4; ++q) {
      int lin = q * 1024 + threadIdx.x * 4;   // element in [32][128]
      int r = lin >> 7;
      int col = lin & 127;
      int v = v0 + r; v = (v < n) ? v : (n - 1);
      float4 f = *(const float4*)(agg + (size_t)v * 128 + col);
      unsigned h0 = rne_bf16(f.x), h1 = rne_bf16(f.y);
      unsigned h2 = rne_bf16(f.z), h3 = rne_bf16(f.w);
      unsigned l0 = rne_bf16(f.x - __uint_as_float(h0 << 16));
      unsigned l1 = rne_bf16(f.y - __uint_as_float(h1 << 16));
      unsigned l2 = rne_bf16(f.z - __uint_as_float(h2 << 16));
      unsigned l3 = rne_bf16(f.w - __uint_as_float(h3 << 16));
      int swz = (r & 7) << 4;
      int byteH = (r * 512 + col * 2) ^ swz;
      int byteL = (r * 256 + col * 2) ^ swz;
      *(uint2*)(pAh + byteH) = make_uint2(h0 | (h1 << 16), h2 | (h3 << 16));
      *(uint2*)(pAl + byteL) = make_uint2(l0 | (l1 << 16), l2 | (l3 << 16));
    }
    // ---- stage z rows (bf16 copy), k in [128,256)
#pragma unroll
    for (int q = 0; q < 2; ++q) {
      int lin = q * 2048 + threadIdx.x * 8;   // ushort element in [32][128]
      int r = lin >> 7;
      int col = lin & 127;
      int v = v0 + r; v = (v < n) ? v : (n - 1);
      uint4 d = *(const uint4*)(zb + (size_t)v * 128 + col);
      int byte = (r * 512 + 256 + col * 2) ^ ((r & 7) << 4);
      *(uint4*)(pAh + byte) = d;
    }
    __syncthreads();

#pragma unroll
    for (int s = 0; s < 2; ++s) {
      f32x4 a0 = {0.f, 0.f, 0.f, 0.f};
      f32x4 a1 = {0.f, 0.f, 0.f, 0.f};
      const int rowH = (s * 16 + rl) * 512;
      const int rowL = (s * 16 + rl) * 256;
      const int swz = (rl & 7) << 4;
#pragma unroll
      for (int c = 0; c < 4; ++c) {           // agg half: hi/lo
        int offH = (rowH + c * 64 + g * 16) ^ swz;
        int offL = (rowL + c * 64 + g * 16) ^ swz;
        bf16x8 ah = *(const bf16x8*)(pAh + offH);
        bf16x8 al = *(const bf16x8*)(pAl + offL);
        a0 = MFMA16(ah, Bh0[c], a0); a1 = MFMA16(ah, Bh1[c], a1);
        a0 = MFMA16(ah, Bl0[c], a0); a1 = MFMA16(ah, Bl1[c], a1);
        a0 = MFMA16(al, Bh0[c], a0); a1 = MFMA16(al, Bh1[c], a1);
      }
#pragma unroll
      for (int c = 4; c < 8; ++c) {           // z half: single bf16
        int offH = (rowH + c * 64 + g * 16) ^ swz;
        bf16x8 ah = *(const bf16x8*)(pAh + offH);
        a0 = MFMA16(ah, Bh0[c], a0); a1 = MFMA16(ah, Bh1[c], a1);
        a0 = MFMA16(ah, Bl0[c], a0); a1 = MFMA16(ah, Bl1[c], a1);
      }
      float pr[4];
#pragma unroll
      for (int j = 0; j < 4; ++j) {
        a0[j] += b0; a1[j] += b1;
        pr[j] = a0[j] * a0[j] + a1[j] * a1[j];
      }
#pragma unroll
      for (int m = 1; m < 16; m <<= 1) {
#pragma unroll
        for (int j = 0; j < 4; ++j) pr[j] += __shfl_xor(pr[j], m);
      }
      if (rl == 0) {
#pragma unroll
        for (int j = 0; j < 4; ++j) psum[s][wv][g * 4 + j] = pr[j];
      }
      __syncthreads();
#pragma unroll
      for (int j = 0; j < 4; ++j) {
        int row16 = g * 4 + j;
        float tot = psum[s][0][row16] + psum[s][1][row16] +
                    psum[s][2][row16] + psum[s][3][row16];
        float inv = 1.0f / fmaxf(sqrtf(tot), 1e-12f);
        int v = v0 + s * 16 + row16;
        if (v < n) {
          float o0 = fmaxf(a0[j] * inv, 0.f);
          float o1 = fmaxf(a1[j] * inv, 0.f);
          out_bf[(size_t)v * 128 + t0 * 16 + rl] = (unsigned short)rne_bf16(o0);
          out_bf[(size_t)v * 128 + t1 * 16 + rl] = (unsigned short)rne_bf16(o1);
        }
      }
    }
    __syncthreads();
  }
}

// ---------------- final linear: [N,128](bf16) @ [128,40] + b ----------------
__global__ __launch_bounds__(256) void final_linear_k(
    const unsigned short* __restrict__ zb, const float* __restrict__ WlinT,
    const float* __restrict__ blin, float* __restrict__ out, int n) {
  __shared__ float wt[128 * 40 + 64];
  __shared__ float bs[40];
  for (int i = threadIdx.x; i < 128 * 40; i += 256) wt[i] = WlinT[i];
  if (threadIdx.x < 40) bs[threadIdx.x] = blin[threadIdx.x];
  __syncthreads();

  int lane = threadIdx.x & 63;
  int c = lane < 40 ? lane : 0;
  int wid = (blockIdx.x * 256 + threadIdx.x) >> 6;
  int nw = (gridDim.x * 256) >> 6;
  for (int v = wid; v < n; v += nw) {
    unsigned u = *(const unsigned*)(zb + (size_t)v * 128 + lane * 2);
    float acc = bs[c];
#pragma unroll 16
    for (int k = 0; k < 64; k++) {
      unsigned w0 = (unsigned)__builtin_amdgcn_readlane((int)u, k);
      acc = fmaf(bf_lo(w0), wt[(2 * k) * 40 + c], acc);
      acc = fmaf(bf_hi(w0), wt[(2 * k + 1) * 40 + c], acc);
    }
    if (lane < 40) out[(size_t)v * 40 + lane] = acc;
  }
}

// ---------------- launch ----------------

extern "C" void kernel_launch(void* const* d_in, const int* in_sizes, int n_in,
                              void* d_out, int out_size, void* d_ws, size_t ws_size,
                              hipStream_t stream) {
  const float* x    = (const float*)d_in[0];
  const int*   ei   = (const int*)d_in[1];
  const float* Wl   = (const float*)d_in[2];
  const float* bl   = (const float*)d_in[3];
  const float* Wr   = (const float*)d_in[4];
  const float* Wlin = (const float*)d_in[5];
  const float* blin = (const float*)d_in[6];

  const int N = in_sizes[0] / 128;
  const int E = in_sizes[1] / 2;
  const int D = 128;
  const int NC = (N + 1023) >> 10;           // coarse buckets (<=128)

  const int* src = ei;
  const int* dstp = ei + E;

  // workspace layout
  unsigned short* planeA = (unsigned short*)d_ws;            // N*128 bf16
  unsigned short* planeB = planeA + (size_t)N * D;           // N*128 bf16
  float* bufA    = (float*)(planeB + (size_t)N * D);         // N*128 fp32 (agg)
  float* inv_cnt = bufA + (size_t)N * D;                     // N
  float* WlinT   = inv_cnt + N;                              // 5120
  unsigned short* Wfrag = (unsigned short*)(WlinT + 5120);   // 3*65536
  int*   offsets = (int*)(Wfrag + 3 * 65536);                // N+1
  int*   cnt     = offsets + N + 1;                          // N
  int*   esrc    = cnt + N;                                  // E
  unsigned* coarse = (unsigned*)(esrc + E);                  // E
  int*   gcur    = (int*)(coarse + E);                       // 128
  int*   bsums   = gcur + 128;                               // <=64

  const int nb = (N + 2047) / 2048;

  // CSR build
  hipMemsetAsync(cnt, 0, (size_t)N * 4, stream);
  count_deg_k<<<(E + 255) / 256, 256, 0, stream>>>(dstp, cnt, E);
  scan1_k<<<nb, 256, 0, stream>>>(cnt, bsums, N);
  scan2_k<<<1, 64, 0, stream>>>(bsums, nb);
  scan3_k<<<nb, 256, 0, stream>>>(cnt, bsums, offsets, inv_cnt, N, E);
  gcur_init_k<<<1, 128, 0, stream>>>(offsets, gcur, N, NC);
  bucketA_k<<<(E + 2047) / 2048, 256, 0, stream>>>(src, dstp, gcur, coarse, E, NC);
  bucketB_k<<<NC, 256, 0, stream>>>(offsets, coarse, esrc, N);

  // weight prep + bf16 x plane
  wfrag_prep_k<<<96, 256, 0, stream>>>(Wl, Wr, Wfrag);
  transpose_lin_k<<<(40 * 128 + 255) / 256, 256, 0, stream>>>(Wlin, WlinT);
  to_bf16_k<<<((N * 32) + 255) / 256, 256, 0, stream>>>((const float4*)x, (uint2*)planeA, N * 32);

  const int aggGrid = (int)(((size_t)N * 64 + 255) / 256);
  const int ntiles = (N + 31) / 32;
  const int sageGrid = 512;

  // layer 1
  aggregate_k<<<aggGrid, 256, 0, stream>>>(planeA, offsets, esrc, inv_cnt, bufA, N);
  sage_layer_mfma_k<<<sageGrid, 256, 0, stream>>>(planeA, bufA, Wfrag + 0 * 65536, bl + 0 * D, planeB, N, ntiles);
  // layer 2
  aggregate_k<<<aggGrid, 256, 0, stream>>>(planeB, offsets, esrc, inv_cnt, bufA, N);
  sage_layer_mfma_k<<<sageGrid, 256, 0, stream>>>(planeB, bufA, Wfrag + 1 * 65536, bl + 1 * D, planeA, N, ntiles);
  // layer 3
  aggregate_k<<<aggGrid, 256, 0, stream>>>(planeA, offsets, esrc, inv_cnt, bufA, N);
  sage_layer_mfma_k<<<sageGrid, 256, 0, stream>>>(planeA, bufA, Wfrag + 2 * 65536, bl + 2 * D, planeB, N, ntiles);

  // final linear
  final_linear_k<<<2048, 256, 0, stream>>>(planeB, WlinT, blin, (float*)d_out, N);
}

// Round 6
// 474.274 us; speedup vs baseline: 1.6590x; 1.1527x over previous
//
#include <hip/hip_runtime.h>

// ---------------------------------------------------------------------------
// GraphSAGE 3-layer forward.
//   CSR build (two-pass LDS-staged bucket) -> bf16 planes -> per-layer:
//   aggregate(mean, half-wave rows) -> MFMA GEMM [agg(hi/lo)|z(bf16)]@[Wl;Wr]^T
//   + bias + L2norm + relu -> final linear (MFMA, 3 col-tiles).
// ---------------------------------------------------------------------------

typedef __bf16 bf16x8 __attribute__((ext_vector_type(8)));
typedef float  f32x4  __attribute__((ext_vector_type(4)));

#define MFMA16(a, b, c) __builtin_amdgcn_mfma_f32_16x16x32_bf16((a), (b), (c), 0, 0, 0)

__device__ __forceinline__ unsigned rne_bf16(float f) {
  unsigned u = __float_as_uint(f);
  unsigned r = u + 0x7FFFu + ((u >> 16) & 1u);
  return r >> 16;
}

__device__ __forceinline__ float bf_lo(unsigned u) { return __uint_as_float(u << 16); }
__device__ __forceinline__ float bf_hi(unsigned u) { return __uint_as_float(u & 0xFFFF0000u); }

// ---------------- CSR build ----------------

__global__ void count_deg_k(const int* __restrict__ dst, int* __restrict__ cnt, int E) {
  int e = blockIdx.x * 256 + threadIdx.x;
  if (e < E) atomicAdd(&cnt[dst[e]], 1);
}

__global__ void scan1_k(const int* __restrict__ cnt, int* __restrict__ bsums, int n) {
  __shared__ int sd[256];
  int base = blockIdx.x * 2048 + threadIdx.x * 8;
  int t = 0;
#pragma unroll
  for (int i = 0; i < 8; i++) { int idx = base + i; if (idx < n) t += cnt[idx]; }
  sd[threadIdx.x] = t; __syncthreads();
  for (int off = 128; off > 0; off >>= 1) {
    if (threadIdx.x < off) sd[threadIdx.x] += sd[threadIdx.x + off];
    __syncthreads();
  }
  if (threadIdx.x == 0) bsums[blockIdx.x] = sd[0];
}

__global__ void scan2_k(int* bsums, int nb) {
  if (blockIdx.x == 0 && threadIdx.x == 0) {
    int run = 0;
    for (int b = 0; b < nb; b++) { int t = bsums[b]; bsums[b] = run; run += t; }
  }
}

__global__ void scan3_k(const int* __restrict__ cnt, const int* __restrict__ bsums,
                        int* __restrict__ offsets, float* __restrict__ inv_cnt,
                        int n, int E) {
  __shared__ int sd[256];
  int base = blockIdx.x * 2048 + threadIdx.x * 8;
  int loc[8]; int t = 0;
#pragma unroll
  for (int i = 0; i < 8; i++) { int idx = base + i; loc[i] = (idx < n) ? cnt[idx] : 0; t += loc[i]; }
  sd[threadIdx.x] = t; __syncthreads();
  for (int off = 1; off < 256; off <<= 1) {
    int u = (threadIdx.x >= (unsigned)off) ? sd[threadIdx.x - off] : 0;
    __syncthreads();
    sd[threadIdx.x] += u;
    __syncthreads();
  }
  int run = bsums[blockIdx.x] + sd[threadIdx.x] - t;
#pragma unroll
  for (int i = 0; i < 8; i++) {
    int idx = base + i;
    if (idx < n) {
      offsets[idx] = run;
      int c = loc[i] > 1 ? loc[i] : 1;
      inv_cnt[idx] = 1.0f / (float)c;
      run += loc[i];
    }
  }
  if (blockIdx.x == 0 && threadIdx.x == 0) offsets[n] = E;
}

// gcur[b] = offsets[min(b*1024, N)]
__global__ void gcur_init_k(const int* __restrict__ offsets, int* __restrict__ gcur,
                            int n, int nc) {
  int b = threadIdx.x;
  if (b < nc) {
    int v = b * 1024; if (v > n) v = n;
    gcur[b] = offsets[v];
  }
}

// ---- bucket pass A: coarse bucket by dst>>10, LDS-staged, contiguous flush
// pack = src | ((dst & 1023) << 17); requires N < 2^17.
__global__ __launch_bounds__(256) void bucketA_k(
    const int* __restrict__ src, const int* __restrict__ dst,
    int* __restrict__ gcur, unsigned* __restrict__ coarse, int E, int nc) {
  __shared__ int hist[128];
  __shared__ int sd[128];
  __shared__ int lpos[128];
  __shared__ int gbase[128];
  __shared__ unsigned stage[2048];
  __shared__ unsigned char sbuck[2048];

  const int tid = threadIdx.x;
  const int e0 = blockIdx.x * 2048;

  if (tid < 128) hist[tid] = 0;
  __syncthreads();

  int bv[8], pk[8];
#pragma unroll
  for (int j = 0; j < 8; ++j) {
    int e = e0 + j * 256 + tid;
    bv[j] = -1;
    if (e < E) {
      int s = src[e], d = dst[e];
      bv[j] = d >> 10;
      pk[j] = s | ((d & 1023) << 17);
      atomicAdd(&hist[bv[j]], 1);
    }
  }
  __syncthreads();

  // inclusive scan of hist[128]
  if (tid < 128) sd[tid] = hist[tid];
  __syncthreads();
  for (int off = 1; off < 128; off <<= 1) {
    int t = 0;
    if (tid < 128 && tid >= off) t = sd[tid - off];
    __syncthreads();
    if (tid < 128) sd[tid] += t;
    __syncthreads();
  }
  if (tid < 128) {
    int excl = sd[tid] - hist[tid];
    lpos[tid] = excl;
    gbase[tid] = (tid < nc && hist[tid] > 0) ? atomicAdd(&gcur[tid], hist[tid]) : 0;
  }
  __syncthreads();

  // local bucket-sort into stage
#pragma unroll
  for (int j = 0; j < 8; ++j) {
    if (bv[j] >= 0) {
      int slot = atomicAdd(&lpos[bv[j]], 1);
      stage[slot] = (unsigned)pk[j];
      sbuck[slot] = (unsigned char)bv[j];
    }
  }
  __syncthreads();

  const int total = sd[127];
  for (int i = tid; i < total; i += 256) {
    int b = sbuck[i];
    int excl = sd[b] - hist[b];
    coarse[gbase[b] + (i - excl)] = stage[i];
  }
}

// ---- bucket pass B: one block per coarse bucket, LDS per-node cursors
__global__ __launch_bounds__(256) void bucketB_k(
    const int* __restrict__ offsets, const unsigned* __restrict__ coarse,
    int* __restrict__ esrc, int n) {
  __shared__ int cur[1024];
  const int b = blockIdx.x;
  const int base = b * 1024;
  const int nn = (n - base < 1024) ? (n - base) : 1024;
  for (int j = threadIdx.x; j < nn; j += 256) cur[j] = offsets[base + j];
  __syncthreads();
  const int beg = offsets[base];
  const int end = offsets[base + nn];
  for (int idx = beg + threadIdx.x; idx < end; idx += 256) {
    unsigned p = coarse[idx];
    int dl = (int)(p >> 17);
    int s = (int)(p & 0x1FFFFu);
    int pos = atomicAdd(&cur[dl], 1);
    esrc[pos] = s;
  }
}

// ---------------- fp32 -> bf16 plane ----------------
__global__ void to_bf16_k(const float4* __restrict__ in, uint2* __restrict__ out, int n4) {
  int i = blockIdx.x * 256 + threadIdx.x;
  if (i >= n4) return;
  float4 f = in[i];
  uint2 o;
  o.x = rne_bf16(f.x) | (rne_bf16(f.y) << 16);
  o.y = rne_bf16(f.z) | (rne_bf16(f.w) << 16);
  out[i] = o;
}

// ---------------- weight fragment prep (hi/lo bf16, MFMA B-layout) ----------
__global__ void wfrag_prep_k(const float* __restrict__ Wl, const float* __restrict__ Wr,
                             unsigned short* __restrict__ wfrag) {
  int id = blockIdx.x * 256 + threadIdx.x;
  if (id >= 3 * 2 * 8 * 8 * 64) return;
  int l = id & 63;
  int c = (id >> 6) & 7;
  int t = (id >> 9) & 7;
  int p = (id >> 12) & 1;
  int layer = id >> 13;
  int col = t * 16 + (l & 15);
  int kbase = c * 32 + (l >> 4) * 8;
  unsigned short* dst = wfrag + (size_t)layer * 65536 +
                        ((((size_t)p * 8 + t) * 8 + c) * 64 + l) * 8;
#pragma unroll
  for (int j = 0; j < 8; ++j) {
    int k = kbase + j;
    float w = (k < 128) ? Wl[layer * 16384 + col * 128 + k]
                        : Wr[layer * 16384 + col * 128 + (k - 128)];
    unsigned h = rne_bf16(w);
    unsigned o;
    if (p == 0) o = h;
    else o = rne_bf16(w - __uint_as_float(h << 16));
    dst[j] = (unsigned short)o;
  }
}

// ---- Wlin -> B-fragments, hi-only bf16, 3 col-tiles of 16 (cols >=40 zero)
// wlf[((t*4 + c)*64 + l)*8 + j] = B[k = c*32+(l>>4)*8+j][col = t*16+(l&15)]
__global__ void wlin_frag_k(const float* __restrict__ Wlin, unsigned short* __restrict__ wlf) {
  int id = blockIdx.x * 256 + threadIdx.x;
  if (id >= 3 * 4 * 64) return;
  int l = id & 63;
  int c = (id >> 6) & 3;
  int t = id >> 8;
  int col = t * 16 + (l & 15);
  int kbase = c * 32 + (l >> 4) * 8;
  unsigned short* dst = wlf + (size_t)id * 8;
#pragma unroll
  for (int j = 0; j < 8; ++j) {
    float w = (col < 40) ? Wlin[col * 128 + kbase + j] : 0.f;
    dst[j] = (unsigned short)rne_bf16(w);
  }
}

// ---------------- aggregation: one wave per node, 2 rows per load ----------
__global__ void aggregate_k(const unsigned short* __restrict__ zb,
                            const int* __restrict__ offsets,
                            const int* __restrict__ esrc,
                            const float* __restrict__ inv_cnt,
                            float* __restrict__ agg, int n) {
  int w = (blockIdx.x * 256 + threadIdx.x) >> 6;
  int lane = threadIdx.x & 63;
  if (w >= n) return;
  int beg = offsets[w], end = offsets[w + 1];
  int cnt = end - beg;
  int half = lane >> 5;
  int l32 = lane & 31;
  float a0 = 0.f, a1 = 0.f, a2 = 0.f, a3 = 0.f;
  int t = 0;
  for (; t + 8 <= cnt; t += 8) {
#pragma unroll
    for (int u = 0; u < 4; ++u) {
      int s = esrc[beg + t + 2 * u + half];
      uint2 d = *(const uint2*)(zb + (size_t)s * 128 + l32 * 4);
      a0 += bf_lo(d.x); a1 += bf_hi(d.x);
      a2 += bf_lo(d.y); a3 += bf_hi(d.y);
    }
  }
  for (; t < cnt; t += 2) {
    int e = t + half;
    float m = (e < cnt) ? 1.f : 0.f;
    int ec = (e < cnt) ? (beg + e) : (end - 1);
    int s = esrc[ec];
    uint2 d = *(const uint2*)(zb + (size_t)s * 128 + l32 * 4);
    a0 = fmaf(m, bf_lo(d.x), a0); a1 = fmaf(m, bf_hi(d.x), a1);
    a2 = fmaf(m, bf_lo(d.y), a2); a3 = fmaf(m, bf_hi(d.y), a3);
  }
  a0 += __shfl_xor(a0, 32); a1 += __shfl_xor(a1, 32);
  a2 += __shfl_xor(a2, 32); a3 += __shfl_xor(a3, 32);
  if (half == 0) {
    float ic = inv_cnt[w];
    float4 o = make_float4(a0 * ic, a1 * ic, a2 * ic, a3 * ic);
    *(float4*)(agg + (size_t)w * 128 + l32 * 4) = o;
  }
}

// ---------------- SAGE layer via MFMA ----------------
__global__ __launch_bounds__(256, 2) void sage_layer_mfma_k(
    const unsigned short* __restrict__ zb, const float* __restrict__ agg,
    const unsigned short* __restrict__ wf, const float* __restrict__ bl,
    unsigned short* __restrict__ out_bf, int n, int ntiles) {
  __shared__ unsigned short Ah_s[32 * 256];   // 16 KB swizzled [32][256]
  __shared__ unsigned short Al_s[32 * 128];   // 8 KB  swizzled [32][128]
  __shared__ float psum[2][4][16];

  const int lane = threadIdx.x & 63;
  const int wv = threadIdx.x >> 6;
  const int g = lane >> 4;
  const int rl = lane & 15;

  const bf16x8* wfv = (const bf16x8*)wf;
  const int t0 = wv * 2, t1 = wv * 2 + 1;
  bf16x8 Bh0[8], Bh1[8], Bl0[8], Bl1[8];
#pragma unroll
  for (int c = 0; c < 8; ++c) {
    Bh0[c] = wfv[((0 * 8 + t0) * 8 + c) * 64 + lane];
    Bh1[c] = wfv[((0 * 8 + t1) * 8 + c) * 64 + lane];
    Bl0[c] = wfv[((1 * 8 + t0) * 8 + c) * 64 + lane];
    Bl1[c] = wfv[((1 * 8 + t1) * 8 + c) * 64 + lane];
  }
  const float b0 = bl[t0 * 16 + rl];
  const float b1 = bl[t1 * 16 + rl];

  char* pAh = (char*)Ah_s;
  char* pAl = (char*)Al_s;

  for (int tile = blockIdx.x; tile < ntiles; tile += gridDim.x) {
    const int v0 = tile * 32;

    // ---- stage agg rows (hi/lo split), k in [0,128)
#pragma unroll
    for (int q = 0; q < 4; ++q) {
      int lin = q * 1024 + threadIdx.x * 4;
      int r = lin >> 7;
      int col = lin & 127;
      int v = v0 + r; v = (v < n) ? v : (n - 1);
      float4 f = *(const float4*)(agg + (size_t)v * 128 + col);
      unsigned h0 = rne_bf16(f.x), h1 = rne_bf16(f.y);
      unsigned h2 = rne_bf16(f.z), h3 = rne_bf16(f.w);
      unsigned l0 = rne_bf16(f.x - __uint_as_float(h0 << 16));
      unsigned l1 = rne_bf16(f.y - __uint_as_float(h1 << 16));
      unsigned l2 = rne_bf16(f.z - __uint_as_float(h2 << 16));
      unsigned l3 = rne_bf16(f.w - __uint_as_float(h3 << 16));
      int swz = (r & 7) << 4;
      int byteH = (r * 512 + col * 2) ^ swz;
      int byteL = (r * 256 + col * 2) ^ swz;
      *(uint2*)(pAh + byteH) = make_uint2(h0 | (h1 << 16), h2 | (h3 << 16));
      *(uint2*)(pAl + byteL) = make_uint2(l0 | (l1 << 16), l2 | (l3 << 16));
    }
    // ---- stage z rows (bf16 copy), k in [128,256)
#pragma unroll
    for (int q = 0; q < 2; ++q) {
      int lin = q * 2048 + threadIdx.x * 8;
      int r = lin >> 7;
      int col = lin & 127;
      int v = v0 + r; v = (v < n) ? v : (n - 1);
      uint4 d = *(const uint4*)(zb + (size_t)v * 128 + col);
      int byte = (r * 512 + 256 + col * 2) ^ ((r & 7) << 4);
      *(uint4*)(pAh + byte) = d;
    }
    __syncthreads();

#pragma unroll
    for (int s = 0; s < 2; ++s) {
      f32x4 a0 = {0.f, 0.f, 0.f, 0.f};
      f32x4 a1 = {0.f, 0.f, 0.f, 0.f};
      const int rowH = (s * 16 + rl) * 512;
      const int rowL = (s * 16 + rl) * 256;
      const int swz = (rl & 7) << 4;
#pragma unroll
      for (int c = 0; c < 4; ++c) {           // agg half: hi/lo
        int offH = (rowH + c * 64 + g * 16) ^ swz;
        int offL = (rowL + c * 64 + g * 16) ^ swz;
        bf16x8 ah = *(const bf16x8*)(pAh + offH);
        bf16x8 al = *(const bf16x8*)(pAl + offL);
        a0 = MFMA16(ah, Bh0[c], a0); a1 = MFMA16(ah, Bh1[c], a1);
        a0 = MFMA16(ah, Bl0[c], a0); a1 = MFMA16(ah, Bl1[c], a1);
        a0 = MFMA16(al, Bh0[c], a0); a1 = MFMA16(al, Bh1[c], a1);
      }
#pragma unroll
      for (int c = 4; c < 8; ++c) {           // z half: single bf16
        int offH = (rowH + c * 64 + g * 16) ^ swz;
        bf16x8 ah = *(const bf16x8*)(pAh + offH);
        a0 = MFMA16(ah, Bh0[c], a0); a1 = MFMA16(ah, Bh1[c], a1);
        a0 = MFMA16(ah, Bl0[c], a0); a1 = MFMA16(ah, Bl1[c], a1);
      }
      float pr[4];
#pragma unroll
      for (int j = 0; j < 4; ++j) {
        a0[j] += b0; a1[j] += b1;
        pr[j] = a0[j] * a0[j] + a1[j] * a1[j];
      }
#pragma unroll
      for (int m = 1; m < 16; m <<= 1) {
#pragma unroll
        for (int j = 0; j < 4; ++j) pr[j] += __shfl_xor(pr[j], m);
      }
      if (rl == 0) {
#pragma unroll
        for (int j = 0; j < 4; ++j) psum[s][wv][g * 4 + j] = pr[j];
      }
      __syncthreads();
#pragma unroll
      for (int j = 0; j < 4; ++j) {
        int row16 = g * 4 + j;
        float tot = psum[s][0][row16] + psum[s][1][row16] +
                    psum[s][2][row16] + psum[s][3][row16];
        float inv = 1.0f / fmaxf(sqrtf(tot), 1e-12f);
        int v = v0 + s * 16 + row16;
        if (v < n) {
          float o0 = fmaxf(a0[j] * inv, 0.f);
          float o1 = fmaxf(a1[j] * inv, 0.f);
          out_bf[(size_t)v * 128 + t0 * 16 + rl] = (unsigned short)rne_bf16(o0);
          out_bf[(size_t)v * 128 + t1 * 16 + rl] = (unsigned short)rne_bf16(o1);
        }
      }
    }
    __syncthreads();
  }
}

// ---------------- final linear via MFMA: [N,128](bf16) @ [128,40] + b ------
// Block: 256 thr / 4 waves / 64 nodes. Wave wv owns node-subtile wv (16 rows),
// computes 3 col-tiles (cols 0..47, 40..47 zero-padded).
__global__ __launch_bounds__(256, 4) void final_linear_mfma_k(
    const unsigned short* __restrict__ zb, const unsigned short* __restrict__ wlf,
    const float* __restrict__ blin, float* __restrict__ out, int n, int ntiles) {
  __shared__ unsigned short Az[64 * 128];   // 16 KB swizzled [64 rows][128 k]

  const int lane = threadIdx.x & 63;
  const int wv = threadIdx.x >> 6;
  const int g = lane >> 4;
  const int rl = lane & 15;

  const bf16x8* wv8 = (const bf16x8*)wlf;
  bf16x8 B[3][4];
#pragma unroll
  for (int t = 0; t < 3; ++t)
#pragma unroll
    for (int c = 0; c < 4; ++c) B[t][c] = wv8[(t * 4 + c) * 64 + lane];
  float bias[3];
#pragma unroll
  for (int t = 0; t < 3; ++t) {
    int col = t * 16 + rl;
    bias[t] = (col < 40) ? blin[col] : 0.f;
  }

  char* pAz = (char*)Az;

  for (int tile = blockIdx.x; tile < ntiles; tile += gridDim.x) {
    const int v0 = tile * 64;
    // stage 64 rows x 256 B, swizzled
#pragma unroll
    for (int q = 0; q < 4; ++q) {
      int lin = q * 2048 + threadIdx.x * 8;   // ushort idx in [64][128]
      int r = lin >> 7;
      int col = lin & 127;
      int v = v0 + r; v = (v < n) ? v : (n - 1);
      uint4 d = *(const uint4*)(zb + (size_t)v * 128 + col);
      int byte = (r * 256 + col * 2) ^ ((r & 7) << 4);
      *(uint4*)(pAz + byte) = d;
    }
    __syncthreads();

    f32x4 acc0 = {0.f, 0.f, 0.f, 0.f};
    f32x4 acc1 = {0.f, 0.f, 0.f, 0.f};
    f32x4 acc2 = {0.f, 0.f, 0.f, 0.f};
    const int rowB = (wv * 16 + rl) * 256;
    const int swz = (rl & 7) << 4;
#pragma unroll
    for (int c = 0; c < 4; ++c) {
      int off = (rowB + c * 64 + g * 16) ^ swz;
      bf16x8 a = *(const bf16x8*)(pAz + off);
      acc0 = MFMA16(a, B[0][c], acc0);
      acc1 = MFMA16(a, B[1][c], acc1);
      acc2 = MFMA16(a, B[2][c], acc2);
    }
#pragma unroll
    for (int j = 0; j < 4; ++j) {
      int v = v0 + wv * 16 + g * 4 + j;
      if (v < n) {
        float* op = out + (size_t)v * 40;
        op[rl] = acc0[j] + bias[0];
        op[16 + rl] = acc1[j] + bias[1];
        if (rl < 8) op[32 + rl] = acc2[j] + bias[2];
      }
    }
    __syncthreads();
  }
}

// ---------------- launch ----------------

extern "C" void kernel_launch(void* const* d_in, const int* in_sizes, int n_in,
                              void* d_out, int out_size, void* d_ws, size_t ws_size,
                              hipStream_t stream) {
  const float* x    = (const float*)d_in[0];
  const int*   ei   = (const int*)d_in[1];
  const float* Wl   = (const float*)d_in[2];
  const float* bl   = (const float*)d_in[3];
  const float* Wr   = (const float*)d_in[4];
  const float* Wlin = (const float*)d_in[5];
  const float* blin = (const float*)d_in[6];

  const int N = in_sizes[0] / 128;
  const int E = in_sizes[1] / 2;
  const int D = 128;
  const int NC = (N + 1023) >> 10;           // coarse buckets (<=128)

  const int* src = ei;
  const int* dstp = ei + E;

  // workspace layout
  unsigned short* planeA = (unsigned short*)d_ws;            // N*128 bf16
  unsigned short* planeB = planeA + (size_t)N * D;           // N*128 bf16
  float* bufA    = (float*)(planeB + (size_t)N * D);         // N*128 fp32 (agg)
  float* inv_cnt = bufA + (size_t)N * D;                     // N
  unsigned short* wlf = (unsigned short*)(inv_cnt + N);      // 6144 ushorts
  unsigned short* Wfrag = wlf + 6144;                        // 3*65536
  int*   offsets = (int*)(Wfrag + 3 * 65536);                // N+1
  int*   cnt     = offsets + N + 1;                          // N
  int*   esrc    = cnt + N;                                  // E
  unsigned* coarse = (unsigned*)(esrc + E);                  // E
  int*   gcur    = (int*)(coarse + E);                       // 128
  int*   bsums   = gcur + 128;                               // <=64

  const int nb = (N + 2047) / 2048;

  // CSR build
  hipMemsetAsync(cnt, 0, (size_t)N * 4, stream);
  count_deg_k<<<(E + 255) / 256, 256, 0, stream>>>(dstp, cnt, E);
  scan1_k<<<nb, 256, 0, stream>>>(cnt, bsums, N);
  scan2_k<<<1, 64, 0, stream>>>(bsums, nb);
  scan3_k<<<nb, 256, 0, stream>>>(cnt, bsums, offsets, inv_cnt, N, E);
  gcur_init_k<<<1, 128, 0, stream>>>(offsets, gcur, N, NC);
  bucketA_k<<<(E + 2047) / 2048, 256, 0, stream>>>(src, dstp, gcur, coarse, E, NC);
  bucketB_k<<<NC, 256, 0, stream>>>(offsets, coarse, esrc, N);

  // weight prep + bf16 x plane
  wfrag_prep_k<<<96, 256, 0, stream>>>(Wl, Wr, Wfrag);
  wlin_frag_k<<<3, 256, 0, stream>>>(Wlin, wlf);
  to_bf16_k<<<((N * 32) + 255) / 256, 256, 0, stream>>>((const float4*)x, (uint2*)planeA, N * 32);

  const int aggGrid = (int)(((size_t)N * 64 + 255) / 256);
  const int ntiles = (N + 31) / 32;
  const int sageGrid = 512;

  // layer 1
  aggregate_k<<<aggGrid, 256, 0, stream>>>(planeA, offsets, esrc, inv_cnt, bufA, N);
  sage_layer_mfma_k<<<sageGrid, 256, 0, stream>>>(planeA, bufA, Wfrag + 0 * 65536, bl + 0 * D, planeB, N, ntiles);
  // layer 2
  aggregate_k<<<aggGrid, 256, 0, stream>>>(planeB, offsets, esrc, inv_cnt, bufA, N);
  sage_layer_mfma_k<<<sageGrid, 256, 0, stream>>>(planeB, bufA, Wfrag + 1 * 65536, bl + 1 * D, planeA, N, ntiles);
  // layer 3
  aggregate_k<<<aggGrid, 256, 0, stream>>>(planeA, offsets, esrc, inv_cnt, bufA, N);
  sage_layer_mfma_k<<<sageGrid, 256, 0, stream>>>(planeA, bufA, Wfrag + 2 * 65536, bl + 2 * D, planeB, N, ntiles);

  // final linear (MFMA)
  const int ntiles64 = (N + 63) / 64;
  final_linear_mfma_k<<<ntiles64, 256, 0, stream>>>(planeB, wlf, blin, (float*)d_out, N, ntiles64);
}

// Round 7
// 416.057 us; speedup vs baseline: 1.8911x; 1.1399x over previous
//
#include <hip/hip_runtime.h>

// ---------------------------------------------------------------------------
// GraphSAGE 3-layer forward.
//   CSR build (coarse-hist + two-pass LDS bucket, no per-node global atomics)
//   -> bf16 planes -> per-layer: aggregate(mean, quarter-wave uint4 rows)
//   -> MFMA GEMM [agg(hi/lo)|z(bf16)]@[Wl;Wr]^T + bias + L2norm + relu
//   -> final linear (MFMA).
// ---------------------------------------------------------------------------

typedef __bf16 bf16x8 __attribute__((ext_vector_type(8)));
typedef float  f32x4  __attribute__((ext_vector_type(4)));

#define MFMA16(a, b, c) __builtin_amdgcn_mfma_f32_16x16x32_bf16((a), (b), (c), 0, 0, 0)

__device__ __forceinline__ unsigned rne_bf16(float f) {
  unsigned u = __float_as_uint(f);
  unsigned r = u + 0x7FFFu + ((u >> 16) & 1u);
  return r >> 16;
}

__device__ __forceinline__ float bf_lo(unsigned u) { return __uint_as_float(u << 16); }
__device__ __forceinline__ float bf_hi(unsigned u) { return __uint_as_float(u & 0xFFFF0000u); }

// ---------------- CSR build ----------------
// pack = src | ((dst & 1023) << 17); requires N < 2^17, N/1024 <= 128.

__global__ __launch_bounds__(256) void histA_k(const int* __restrict__ dst,
                                               int* __restrict__ ghist, int E) {
  __shared__ int h[128];
  const int tid = threadIdx.x;
  if (tid < 128) h[tid] = 0;
  __syncthreads();
  const int e0 = blockIdx.x * 2048;
#pragma unroll
  for (int j = 0; j < 8; ++j) {
    int e = e0 + j * 256 + tid;
    if (e < E) atomicAdd(&h[dst[e] >> 10], 1);
  }
  __syncthreads();
  if (tid < 128 && h[tid]) atomicAdd(&ghist[tid], h[tid]);
}

// 1 block, 128 threads: exclusive scan of ghist -> cbase[0..128], gcur init
__global__ void cscan_k(const int* __restrict__ ghist, int* __restrict__ cbase,
                        int* __restrict__ gcur, int E) {
  __shared__ int sd[128];
  const int tid = threadIdx.x;
  int v = ghist[tid];
  sd[tid] = v;
  __syncthreads();
  for (int off = 1; off < 128; off <<= 1) {
    int u = (tid >= off) ? sd[tid - off] : 0;
    __syncthreads();
    sd[tid] += u;
    __syncthreads();
  }
  int excl = sd[tid] - v;
  cbase[tid] = excl;
  gcur[tid] = excl;
  if (tid == 127) cbase[128] = sd[127];
}

// pass A: coarse bucket by dst>>10, LDS-staged, contiguous flush
__global__ __launch_bounds__(256) void bucketA_k(
    const int* __restrict__ src, const int* __restrict__ dst,
    int* __restrict__ gcur, unsigned* __restrict__ coarse, int E, int nc) {
  __shared__ int hist[128];
  __shared__ int sd[128];
  __shared__ int lpos[128];
  __shared__ int gbase[128];
  __shared__ unsigned stage[2048];
  __shared__ unsigned char sbuck[2048];

  const int tid = threadIdx.x;
  const int e0 = blockIdx.x * 2048;

  if (tid < 128) hist[tid] = 0;
  __syncthreads();

  int bv[8], pk[8];
#pragma unroll
  for (int j = 0; j < 8; ++j) {
    int e = e0 + j * 256 + tid;
    bv[j] = -1;
    if (e < E) {
      int s = src[e], d = dst[e];
      bv[j] = d >> 10;
      pk[j] = s | ((d & 1023) << 17);
      atomicAdd(&hist[bv[j]], 1);
    }
  }
  __syncthreads();

  if (tid < 128) sd[tid] = hist[tid];
  __syncthreads();
  for (int off = 1; off < 128; off <<= 1) {
    int t = 0;
    if (tid < 128 && tid >= off) t = sd[tid - off];
    __syncthreads();
    if (tid < 128) sd[tid] += t;
    __syncthreads();
  }
  if (tid < 128) {
    int excl = sd[tid] - hist[tid];
    lpos[tid] = excl;
    gbase[tid] = (tid < nc && hist[tid] > 0) ? atomicAdd(&gcur[tid], hist[tid]) : 0;
  }
  __syncthreads();

#pragma unroll
  for (int j = 0; j < 8; ++j) {
    if (bv[j] >= 0) {
      int slot = atomicAdd(&lpos[bv[j]], 1);
      stage[slot] = (unsigned)pk[j];
      sbuck[slot] = (unsigned char)bv[j];
    }
  }
  __syncthreads();

  const int total = sd[127];
  for (int i = tid; i < total; i += 256) {
    int b = sbuck[i];
    int excl = sd[b] - hist[b];
    coarse[gbase[b] + (i - excl)] = stage[i];
  }
}

// pass B: one block per coarse bucket. Local hist + scan -> offsets/inv_cnt,
// then scatter esrc within L2-resident window.
__global__ __launch_bounds__(256) void bucketB_k(
    const int* __restrict__ cbase, const unsigned* __restrict__ coarse,
    int* __restrict__ esrc, int* __restrict__ offsets,
    float* __restrict__ inv_cnt, int n, int E) {
  __shared__ int hcnt[1024];
  __shared__ int cur[1024];
  __shared__ int sd[256];

  const int tid = threadIdx.x;
  const int b = blockIdx.x;
  const int base = b * 1024;
  const int nn = (n - base < 1024) ? (n - base) : 1024;
  const int cbeg = cbase[b];
  const int cend = cbase[b + 1];

  for (int j = tid; j < 1024; j += 256) hcnt[j] = 0;
  __syncthreads();
  for (int idx = cbeg + tid; idx < cend; idx += 256)
    atomicAdd(&hcnt[coarse[idx] >> 17], 1);
  __syncthreads();

  // block scan over 1024 bins (4 per thread)
  int b0 = hcnt[tid * 4], b1 = hcnt[tid * 4 + 1];
  int b2 = hcnt[tid * 4 + 2], b3 = hcnt[tid * 4 + 3];
  int tot = b0 + b1 + b2 + b3;
  sd[tid] = tot;
  __syncthreads();
  for (int off = 1; off < 256; off <<= 1) {
    int u = (tid >= off) ? sd[tid - off] : 0;
    __syncthreads();
    sd[tid] += u;
    __syncthreads();
  }
  int excl = cbeg + sd[tid] - tot;
  cur[tid * 4]     = excl;
  cur[tid * 4 + 1] = excl + b0;
  cur[tid * 4 + 2] = excl + b0 + b1;
  cur[tid * 4 + 3] = excl + b0 + b1 + b2;
  __syncthreads();

  for (int j = tid; j < nn; j += 256) {
    offsets[base + j] = cur[j];
    int c = hcnt[j] > 1 ? hcnt[j] : 1;
    inv_cnt[base + j] = 1.0f / (float)c;
  }
  if (tid == 0 && base + nn >= n) offsets[n] = cend;
  __syncthreads();

  for (int idx = cbeg + tid; idx < cend; idx += 256) {
    unsigned p = coarse[idx];
    int pos = atomicAdd(&cur[p >> 17], 1);
    esrc[pos] = (int)(p & 0x1FFFFu);
  }
}

// ---------------- fp32 -> bf16 plane ----------------
__global__ void to_bf16_k(const float4* __restrict__ in, uint2* __restrict__ out, int n4) {
  int i = blockIdx.x * 256 + threadIdx.x;
  if (i >= n4) return;
  float4 f = in[i];
  uint2 o;
  o.x = rne_bf16(f.x) | (rne_bf16(f.y) << 16);
  o.y = rne_bf16(f.z) | (rne_bf16(f.w) << 16);
  out[i] = o;
}

// ---------------- weight fragment prep (hi/lo bf16, MFMA B-layout) ----------
__global__ void wfrag_prep_k(const float* __restrict__ Wl, const float* __restrict__ Wr,
                             unsigned short* __restrict__ wfrag) {
  int id = blockIdx.x * 256 + threadIdx.x;
  if (id >= 3 * 2 * 8 * 8 * 64) return;
  int l = id & 63;
  int c = (id >> 6) & 7;
  int t = (id >> 9) & 7;
  int p = (id >> 12) & 1;
  int layer = id >> 13;
  int col = t * 16 + (l & 15);
  int kbase = c * 32 + (l >> 4) * 8;
  unsigned short* dst = wfrag + (size_t)layer * 65536 +
                        ((((size_t)p * 8 + t) * 8 + c) * 64 + l) * 8;
#pragma unroll
  for (int j = 0; j < 8; ++j) {
    int k = kbase + j;
    float w = (k < 128) ? Wl[layer * 16384 + col * 128 + k]
                        : Wr[layer * 16384 + col * 128 + (k - 128)];
    unsigned h = rne_bf16(w);
    unsigned o;
    if (p == 0) o = h;
    else o = rne_bf16(w - __uint_as_float(h << 16));
    dst[j] = (unsigned short)o;
  }
}

// Wlin -> B-fragments, hi-only bf16, 3 col-tiles of 16 (cols >=40 zero)
__global__ void wlin_frag_k(const float* __restrict__ Wlin, unsigned short* __restrict__ wlf) {
  int id = blockIdx.x * 256 + threadIdx.x;
  if (id >= 3 * 4 * 64) return;
  int l = id & 63;
  int c = (id >> 6) & 3;
  int t = id >> 8;
  int col = t * 16 + (l & 15);
  int kbase = c * 32 + (l >> 4) * 8;
  unsigned short* dst = wlf + (size_t)id * 8;
#pragma unroll
  for (int j = 0; j < 8; ++j) {
    float w = (col < 40) ? Wlin[col * 128 + kbase + j] : 0.f;
    dst[j] = (unsigned short)rne_bf16(w);
  }
}

// ---------------- aggregation: one wave per node, quarter-wave rows --------
// Quarter q (16 lanes) reads edge stream t+4u+q; lane covers dims
// [l16*8, l16*8+8) via one uint4 (8 bf16). Reduce via shfl_xor(16,32).
__global__ void aggregate_k(const unsigned short* __restrict__ zb,
                            const int* __restrict__ offsets,
                            const int* __restrict__ esrc,
                            const float* __restrict__ inv_cnt,
                            float* __restrict__ agg, int n) {
  int w = (blockIdx.x * 256 + threadIdx.x) >> 6;
  int lane = threadIdx.x & 63;
  if (w >= n) return;
  int beg = offsets[w], end = offsets[w + 1];
  int cnt = end - beg;
  int q = lane >> 4;
  int l16 = lane & 15;
  float a0 = 0.f, a1 = 0.f, a2 = 0.f, a3 = 0.f;
  float a4 = 0.f, a5 = 0.f, a6 = 0.f, a7 = 0.f;
  int t = 0;
  for (; t + 16 <= cnt; t += 16) {
#pragma unroll
    for (int u = 0; u < 4; ++u) {
      int s = esrc[beg + t + 4 * u + q];
      uint4 d = *(const uint4*)(zb + (size_t)s * 128 + l16 * 8);
      a0 += bf_lo(d.x); a1 += bf_hi(d.x);
      a2 += bf_lo(d.y); a3 += bf_hi(d.y);
      a4 += bf_lo(d.z); a5 += bf_hi(d.z);
      a6 += bf_lo(d.w); a7 += bf_hi(d.w);
    }
  }
  for (; t + 4 <= cnt; t += 4) {
    int s = esrc[beg + t + q];
    uint4 d = *(const uint4*)(zb + (size_t)s * 128 + l16 * 8);
    a0 += bf_lo(d.x); a1 += bf_hi(d.x);
    a2 += bf_lo(d.y); a3 += bf_hi(d.y);
    a4 += bf_lo(d.z); a5 += bf_hi(d.z);
    a6 += bf_lo(d.w); a7 += bf_hi(d.w);
  }
  if (t < cnt) {
    int e = t + q;
    float m = (e < cnt) ? 1.f : 0.f;
    int ec = (e < cnt) ? (beg + e) : (end - 1);
    int s = esrc[ec];
    uint4 d = *(const uint4*)(zb + (size_t)s * 128 + l16 * 8);
    a0 = fmaf(m, bf_lo(d.x), a0); a1 = fmaf(m, bf_hi(d.x), a1);
    a2 = fmaf(m, bf_lo(d.y), a2); a3 = fmaf(m, bf_hi(d.y), a3);
    a4 = fmaf(m, bf_lo(d.z), a4); a5 = fmaf(m, bf_hi(d.z), a5);
    a6 = fmaf(m, bf_lo(d.w), a6); a7 = fmaf(m, bf_hi(d.w), a7);
  }
#pragma unroll
  for (int m = 16; m <= 32; m <<= 1) {
    a0 += __shfl_xor(a0, m); a1 += __shfl_xor(a1, m);
    a2 += __shfl_xor(a2, m); a3 += __shfl_xor(a3, m);
    a4 += __shfl_xor(a4, m); a5 += __shfl_xor(a5, m);
    a6 += __shfl_xor(a6, m); a7 += __shfl_xor(a7, m);
  }
  if (q == 0) {
    float ic = inv_cnt[w];
    float* op = agg + (size_t)w * 128 + l16 * 8;
    *(float4*)op = make_float4(a0 * ic, a1 * ic, a2 * ic, a3 * ic);
    *(float4*)(op + 4) = make_float4(a4 * ic, a5 * ic, a6 * ic, a7 * ic);
  }
}

// ---------------- SAGE layer via MFMA ----------------
__global__ __launch_bounds__(256, 2) void sage_layer_mfma_k(
    const unsigned short* __restrict__ zb, const float* __restrict__ agg,
    const unsigned short* __restrict__ wf, const float* __restrict__ bl,
    unsigned short* __restrict__ out_bf, int n, int ntiles) {
  __shared__ unsigned short Ah_s[32 * 256];
  __shared__ unsigned short Al_s[32 * 128];
  __shared__ float psum[2][4][16];

  const int lane = threadIdx.x & 63;
  const int wv = threadIdx.x >> 6;
  const int g = lane >> 4;
  const int rl = lane & 15;

  const bf16x8* wfv = (const bf16x8*)wf;
  const int t0 = wv * 2, t1 = wv * 2 + 1;
  bf16x8 Bh0[8], Bh1[8], Bl0[8], Bl1[8];
#pragma unroll
  for (int c = 0; c < 8; ++c) {
    Bh0[c] = wfv[((0 * 8 + t0) * 8 + c) * 64 + lane];
    Bh1[c] = wfv[((0 * 8 + t1) * 8 + c) * 64 + lane];
    Bl0[c] = wfv[((1 * 8 + t0) * 8 + c) * 64 + lane];
    Bl1[c] = wfv[((1 * 8 + t1) * 8 + c) * 64 + lane];
  }
  const float b0 = bl[t0 * 16 + rl];
  const float b1 = bl[t1 * 16 + rl];

  char* pAh = (char*)Ah_s;
  char* pAl = (char*)Al_s;

  for (int tile = blockIdx.x; tile < ntiles; tile += gridDim.x) {
    const int v0 = tile * 32;

#pragma unroll
    for (int q = 0; q < 4; ++q) {
      int lin = q * 1024 + threadIdx.x * 4;
      int r = lin >> 7;
      int col = lin & 127;
      int v = v0 + r; v = (v < n) ? v : (n - 1);
      float4 f = *(const float4*)(agg + (size_t)v * 128 + col);
      unsigned h0 = rne_bf16(f.x), h1 = rne_bf16(f.y);
      unsigned h2 = rne_bf16(f.z), h3 = rne_bf16(f.w);
      unsigned l0 = rne_bf16(f.x - __uint_as_float(h0 << 16));
      unsigned l1 = rne_bf16(f.y - __uint_as_float(h1 << 16));
      unsigned l2 = rne_bf16(f.z - __uint_as_float(h2 << 16));
      unsigned l3 = rne_bf16(f.w - __uint_as_float(h3 << 16));
      int swz = (r & 7) << 4;
      int byteH = (r * 512 + col * 2) ^ swz;
      int byteL = (r * 256 + col * 2) ^ swz;
      *(uint2*)(pAh + byteH) = make_uint2(h0 | (h1 << 16), h2 | (h3 << 16));
      *(uint2*)(pAl + byteL) = make_uint2(l0 | (l1 << 16), l2 | (l3 << 16));
    }
#pragma unroll
    for (int q = 0; q < 2; ++q) {
      int lin = q * 2048 + threadIdx.x * 8;
      int r = lin >> 7;
      int col = lin & 127;
      int v = v0 + r; v = (v < n) ? v : (n - 1);
      uint4 d = *(const uint4*)(zb + (size_t)v * 128 + col);
      int byte = (r * 512 + 256 + col * 2) ^ ((r & 7) << 4);
      *(uint4*)(pAh + byte) = d;
    }
    __syncthreads();

#pragma unroll
    for (int s = 0; s < 2; ++s) {
      f32x4 a0 = {0.f, 0.f, 0.f, 0.f};
      f32x4 a1 = {0.f, 0.f, 0.f, 0.f};
      const int rowH = (s * 16 + rl) * 512;
      const int rowL = (s * 16 + rl) * 256;
      const int swz = (rl & 7) << 4;
#pragma unroll
      for (int c = 0; c < 4; ++c) {
        int offH = (rowH + c * 64 + g * 16) ^ swz;
        int offL = (rowL + c * 64 + g * 16) ^ swz;
        bf16x8 ah = *(const bf16x8*)(pAh + offH);
        bf16x8 al = *(const bf16x8*)(pAl + offL);
        a0 = MFMA16(ah, Bh0[c], a0); a1 = MFMA16(ah, Bh1[c], a1);
        a0 = MFMA16(ah, Bl0[c], a0); a1 = MFMA16(ah, Bl1[c], a1);
        a0 = MFMA16(al, Bh0[c], a0); a1 = MFMA16(al, Bh1[c], a1);
      }
#pragma unroll
      for (int c = 4; c < 8; ++c) {
        int offH = (rowH + c * 64 + g * 16) ^ swz;
        bf16x8 ah = *(const bf16x8*)(pAh + offH);
        a0 = MFMA16(ah, Bh0[c], a0); a1 = MFMA16(ah, Bh1[c], a1);
        a0 = MFMA16(ah, Bl0[c], a0); a1 = MFMA16(ah, Bl1[c], a1);
      }
      float pr[4];
#pragma unroll
      for (int j = 0; j < 4; ++j) {
        a0[j] += b0; a1[j] += b1;
        pr[j] = a0[j] * a0[j] + a1[j] * a1[j];
      }
#pragma unroll
      for (int m = 1; m < 16; m <<= 1) {
#pragma unroll
        for (int j = 0; j < 4; ++j) pr[j] += __shfl_xor(pr[j], m);
      }
      if (rl == 0) {
#pragma unroll
        for (int j = 0; j < 4; ++j) psum[s][wv][g * 4 + j] = pr[j];
      }
      __syncthreads();
#pragma unroll
      for (int j = 0; j < 4; ++j) {
        int row16 = g * 4 + j;
        float tot = psum[s][0][row16] + psum[s][1][row16] +
                    psum[s][2][row16] + psum[s][3][row16];
        float inv = 1.0f / fmaxf(sqrtf(tot), 1e-12f);
        int v = v0 + s * 16 + row16;
        if (v < n) {
          float o0 = fmaxf(a0[j] * inv, 0.f);
          float o1 = fmaxf(a1[j] * inv, 0.f);
          out_bf[(size_t)v * 128 + t0 * 16 + rl] = (unsigned short)rne_bf16(o0);
          out_bf[(size_t)v * 128 + t1 * 16 + rl] = (unsigned short)rne_bf16(o1);
        }
      }
    }
    __syncthreads();
  }
}

// ---------------- final linear via MFMA ----------------
__global__ __launch_bounds__(256, 4) void final_linear_mfma_k(
    const unsigned short* __restrict__ zb, const unsigned short* __restrict__ wlf,
    const float* __restrict__ blin, float* __restrict__ out, int n, int ntiles) {
  __shared__ unsigned short Az[64 * 128];

  const int lane = threadIdx.x & 63;
  const int wv = threadIdx.x >> 6;
  const int g = lane >> 4;
  const int rl = lane & 15;

  const bf16x8* wv8 = (const bf16x8*)wlf;
  bf16x8 B[3][4];
#pragma unroll
  for (int t = 0; t < 3; ++t)
#pragma unroll
    for (int c = 0; c < 4; ++c) B[t][c] = wv8[(t * 4 + c) * 64 + lane];
  float bias[3];
#pragma unroll
  for (int t = 0; t < 3; ++t) {
    int col = t * 16 + rl;
    bias[t] = (col < 40) ? blin[col] : 0.f;
  }

  char* pAz = (char*)Az;

  for (int tile = blockIdx.x; tile < ntiles; tile += gridDim.x) {
    const int v0 = tile * 64;
#pragma unroll
    for (int q = 0; q < 4; ++q) {
      int lin = q * 2048 + threadIdx.x * 8;
      int r = lin >> 7;
      int col = lin & 127;
      int v = v0 + r; v = (v < n) ? v : (n - 1);
      uint4 d = *(const uint4*)(zb + (size_t)v * 128 + col);
      int byte = (r * 256 + col * 2) ^ ((r & 7) << 4);
      *(uint4*)(pAz + byte) = d;
    }
    __syncthreads();

    f32x4 acc0 = {0.f, 0.f, 0.f, 0.f};
    f32x4 acc1 = {0.f, 0.f, 0.f, 0.f};
    f32x4 acc2 = {0.f, 0.f, 0.f, 0.f};
    const int rowB = (wv * 16 + rl) * 256;
    const int swz = (rl & 7) << 4;
#pragma unroll
    for (int c = 0; c < 4; ++c) {
      int off = (rowB + c * 64 + g * 16) ^ swz;
      bf16x8 a = *(const bf16x8*)(pAz + off);
      acc0 = MFMA16(a, B[0][c], acc0);
      acc1 = MFMA16(a, B[1][c], acc1);
      acc2 = MFMA16(a, B[2][c], acc2);
    }
#pragma unroll
    for (int j = 0; j < 4; ++j) {
      int v = v0 + wv * 16 + g * 4 + j;
      if (v < n) {
        float* op = out + (size_t)v * 40;
        op[rl] = acc0[j] + bias[0];
        op[16 + rl] = acc1[j] + bias[1];
        if (rl < 8) op[32 + rl] = acc2[j] + bias[2];
      }
    }
    __syncthreads();
  }
}

// ---------------- launch ----------------

extern "C" void kernel_launch(void* const* d_in, const int* in_sizes, int n_in,
                              void* d_out, int out_size, void* d_ws, size_t ws_size,
                              hipStream_t stream) {
  const float* x    = (const float*)d_in[0];
  const int*   ei   = (const int*)d_in[1];
  const float* Wl   = (const float*)d_in[2];
  const float* bl   = (const float*)d_in[3];
  const float* Wr   = (const float*)d_in[4];
  const float* Wlin = (const float*)d_in[5];
  const float* blin = (const float*)d_in[6];

  const int N = in_sizes[0] / 128;
  const int E = in_sizes[1] / 2;
  const int D = 128;
  const int NC = (N + 1023) >> 10;           // coarse buckets (<=128)

  const int* src = ei;
  const int* dstp = ei + E;

  // workspace layout
  unsigned short* planeA = (unsigned short*)d_ws;            // N*128 bf16
  unsigned short* planeB = planeA + (size_t)N * D;           // N*128 bf16
  float* bufA    = (float*)(planeB + (size_t)N * D);         // N*128 fp32 (agg)
  float* inv_cnt = bufA + (size_t)N * D;                     // N
  unsigned short* wlf = (unsigned short*)(inv_cnt + N);      // 6144 ushorts
  unsigned short* Wfrag = wlf + 6144;                        // 3*65536
  int*   offsets = (int*)(Wfrag + 3 * 65536);                // N+1
  int*   esrc    = offsets + N + 1;                          // E
  unsigned* coarse = (unsigned*)(esrc + E);                  // E
  int*   cbase   = (int*)(coarse + E);                       // 129
  int*   gcur    = cbase + 129;                              // 128
  int*   ghist   = gcur + 128;                               // 128

  // CSR build (no per-node global atomics)
  hipMemsetAsync(ghist, 0, 128 * 4, stream);
  histA_k<<<(E + 2047) / 2048, 256, 0, stream>>>(dstp, ghist, E);
  cscan_k<<<1, 128, 0, stream>>>(ghist, cbase, gcur, E);
  bucketA_k<<<(E + 2047) / 2048, 256, 0, stream>>>(src, dstp, gcur, coarse, E, NC);
  bucketB_k<<<NC, 256, 0, stream>>>(cbase, coarse, esrc, offsets, inv_cnt, N, E);

  // weight prep + bf16 x plane
  wfrag_prep_k<<<96, 256, 0, stream>>>(Wl, Wr, Wfrag);
  wlin_frag_k<<<3, 256, 0, stream>>>(Wlin, wlf);
  to_bf16_k<<<((N * 32) + 255) / 256, 256, 0, stream>>>((const float4*)x, (uint2*)planeA, N * 32);

  const int aggGrid = (int)(((size_t)N * 64 + 255) / 256);
  const int ntiles = (N + 31) / 32;
  const int sageGrid = 512;

  // layer 1
  aggregate_k<<<aggGrid, 256, 0, stream>>>(planeA, offsets, esrc, inv_cnt, bufA, N);
  sage_layer_mfma_k<<<sageGrid, 256, 0, stream>>>(planeA, bufA, Wfrag + 0 * 65536, bl + 0 * D, planeB, N, ntiles);
  // layer 2
  aggregate_k<<<aggGrid, 256, 0, stream>>>(planeB, offsets, esrc, inv_cnt, bufA, N);
  sage_layer_mfma_k<<<sageGrid, 256, 0, stream>>>(planeB, bufA, Wfrag + 1 * 65536, bl + 1 * D, planeA, N, ntiles);
  // layer 3
  aggregate_k<<<aggGrid, 256, 0, stream>>>(planeA, offsets, esrc, inv_cnt, bufA, N);
  sage_layer_mfma_k<<<sageGrid, 256, 0, stream>>>(planeA, bufA, Wfrag + 2 * 65536, bl + 2 * D, planeB, N, ntiles);

  // final linear (MFMA)
  const int ntiles64 = (N + 63) / 64;
  final_linear_mfma_k<<<ntiles64, 256, 0, stream>>>(planeB, wlf, blin, (float*)d_out, N, ntiles64);
}